// Round 7
// baseline (171.994 us; speedup 1.0000x reference)
//
#include <hip/hip_runtime.h>
#include <hip/hip_fp16.h>
#include <cmath>

#define BATCH 8192

typedef short bf16x8 __attribute__((ext_vector_type(8)));
typedef float f32x4 __attribute__((ext_vector_type(4)));
typedef float f32x16 __attribute__((ext_vector_type(16)));

__device__ __forceinline__ void split2(float x, unsigned short& h, unsigned short& l){
    unsigned u = __float_as_uint(x);
    unsigned hr = u + 0x7fffu + ((u >> 16) & 1u);
    unsigned short hs = (unsigned short)(hr >> 16);
    float hf = __uint_as_float(((unsigned)hs) << 16);
    float d = x - hf;
    unsigned v = __float_as_uint(d);
    unsigned short ls = (unsigned short)((v + 0x7fffu + ((v >> 16) & 1u)) >> 16);
    h = hs; l = ls;
}
__device__ __forceinline__ float fsig(float x){ return 1.f / (1.f + __expf(-x)); }
__device__ __forceinline__ float ftanh(float x){
    x = fminf(fmaxf(x, -10.f), 10.f);
    const float e = __expf(2.f*x);
    return (e - 1.f) / (e + 1.f);
}

// Tiled staged layouts (prepared by prep_all, consumed by fragment-direct loads).
// P:  tile (band in [0,64), ks in [0,16)): image [r(4)][m(128)][8] = 4096 shorts
// W1: tile (nb in [0,8),  ks in [0,16)):  image [r(4)][n(128)][8] = 4096 shorts
// Xp: tile (ks in [0,16)): image [r(4)][n(64)][8] = 2048 shorts
// Wt: tile (ks in [0,16)): image [r(4)][n(128)][8] = 4096 shorts
// The tiled image IS the MFMA fragment order -> fragments load straight from
// global (L2-resident), no LDS bounce, no barriers in the GEMM.

// ---------------------------------------------------------------------------
// Preprocessing, wide-parallel.  grid (102, 16)  (unchanged)
// ---------------------------------------------------------------------------
__global__ __launch_bounds__(256) void prep_all(
    const float* __restrict__ percep,
    const float* __restrict__ in_proj, const float* __restrict__ W_in,
    const float* __restrict__ b_in,
    const float* __restrict__ mu_w, const float* __restrict__ ls_w,
    const float* __restrict__ conv_w, const float* __restrict__ conv_b,
    const float* __restrict__ out_proj, const float* __restrict__ x_proj,
    unsigned short* __restrict__ W1h, unsigned short* __restrict__ W1l,
    unsigned short* __restrict__ Wth, unsigned short* __restrict__ Wtl,
    unsigned short* __restrict__ Xph, unsigned short* __restrict__ Xpl,
    unsigned short* __restrict__ Ph, unsigned short* __restrict__ Pl,
    float* __restrict__ b1)
{
    __shared__ float As[16][33];
    __shared__ float Ws[16][36];
    __shared__ unsigned short Lh[4096];
    __shared__ unsigned short Ll[4096];

    const int bx = blockIdx.x, by = blockIdx.y;
    const int tid = threadIdx.x;

    if (bx >= 38){
        // one (band, ks) tile per block
        const int s = (bx-38)*16 + by;
        const int band = s >> 4, ks = s & 15;
        const size_t tbase = (size_t)s*4096;
#pragma unroll
        for (int g=0; g<2; ++g){
            const int u = g*256 + tid;
            const int row = u >> 2, piece = u & 3;
            const float* src = percep + (size_t)(band*128 + row)*512 + ks*32 + piece*8;
            const float4 v0 = *reinterpret_cast<const float4*>(src);
            const float4 v1 = *reinterpret_cast<const float4*>(src+4);
            unsigned short h[8], l[8];
            split2(v0.x,h[0],l[0]); split2(v0.y,h[1],l[1]);
            split2(v0.z,h[2],l[2]); split2(v0.w,h[3],l[3]);
            split2(v1.x,h[4],l[4]); split2(v1.y,h[5],l[5]);
            split2(v1.z,h[6],l[6]); split2(v1.w,h[7],l[7]);
            uint4 H, L;
            H.x=(unsigned)h[0]|((unsigned)h[1]<<16); H.y=(unsigned)h[2]|((unsigned)h[3]<<16);
            H.z=(unsigned)h[4]|((unsigned)h[5]<<16); H.w=(unsigned)h[6]|((unsigned)h[7]<<16);
            L.x=(unsigned)l[0]|((unsigned)l[1]<<16); L.y=(unsigned)l[2]|((unsigned)l[3]<<16);
            L.z=(unsigned)l[4]|((unsigned)l[5]<<16); L.w=(unsigned)l[6]|((unsigned)l[7]<<16);
            const int off = piece*1024 + row*8;
            *reinterpret_cast<uint4*>(&Lh[off]) = H;
            *reinterpret_cast<uint4*>(&Ll[off]) = L;
        }
        __syncthreads();
#pragma unroll
        for (int g=0; g<2; ++g){
            const int f = g*256 + tid;
            *reinterpret_cast<uint4*>(&Ph[tbase + f*8]) = *reinterpret_cast<const uint4*>(&Lh[f*8]);
            *reinterpret_cast<uint4*>(&Pl[tbase + f*8]) = *reinterpret_cast<const uint4*>(&Ll[f*8]);
        }
        return;
    }
    if (bx == 36){
        // b1[n] = in_proj[n,:].b_in ; 16 blocks x (4 waves x 16 rows)
        const int lane = tid & 63, w = tid >> 6;
        const float4 bv = *reinterpret_cast<const float4*>(&b_in[lane*4]);
        const int nbase = by*64 + w*16;
#pragma unroll 4
        for (int i=0;i<16;i++){
            const int n = nbase + i;
            const float4 av = *reinterpret_cast<const float4*>(&in_proj[(size_t)n*256 + lane*4]);
            float p = av.x*bv.x + av.y*bv.y + av.z*bv.z + av.w*bv.w;
#pragma unroll
            for (int off=32; off; off>>=1) p += __shfl_xor(p, off, 64);
            if (lane == 0)
                b1[n] = (n < 512) ? fmaf(p, conv_w[n*4+3], conv_b[n]) : p;
        }
        return;
    }
    if (bx == 37){
        // Xp: one ks tile (by = ks): cols c0..c0+31, rows 0..63
        const int c0 = by*32;
#pragma unroll
        for (int p=0;p<8;p++){
            const int idx = p*256 + tid;
            const int rrow = idx >> 5;
            const int c = c0 + (idx & 31);
            const float v = (rrow < 48) ? x_proj[(size_t)rrow*512 + c] : 0.f;
            unsigned short h,l; split2(v,h,l);
            const int ks = c >> 5, r = (c >> 3) & 3, pos = c & 7;
            const size_t off = (size_t)ks*2048 + (r*64 + rrow)*8 + pos;
            Xph[off]=h; Xpl[off]=l;
        }
        return;
    }
    // ---- weight GEMM, 32x32 output tile ----
    const float* A; unsigned short *Oh, *Ol; int m0; bool wt;
    const float* B;
    if (bx < 32){ A = in_proj + (size_t)bx*32*256; B = W_in; Oh=W1h; Ol=W1l; m0=bx*32; wt=false; }
    else {
        const int t = bx - 32;
        A = (t < 2) ? (mu_w + (size_t)t*32*256) : (ls_w + (size_t)(t-2)*32*256);
        B = out_proj; Oh=Wth; Ol=Wtl; m0=t*32; wt=true;
    }
    const int n0 = by*32;

    const int tm = tid >> 3, tn = tid & 7;   // 32 rows x 8 col-quads
    float acc[4] = {0.f,0.f,0.f,0.f};

    for (int k0=0;k0<256;k0+=16){
        {
            const int row = tid >> 3, kf = (tid & 7)*2;
            const float2 v = *reinterpret_cast<const float2*>(A + (size_t)row*256 + k0 + kf);
            As[kf][row] = v.x; As[kf+1][row] = v.y;
        }
        {
            const int kk = tid >> 4, c = (tid & 15)*2;
            const float2 v = *reinterpret_cast<const float2*>(B + (size_t)(k0+kk)*512 + n0 + c);
            Ws[kk][c] = v.x; Ws[kk][c+1] = v.y;
        }
        __syncthreads();
#pragma unroll
        for (int k=0;k<16;k++){
            const float a = As[k][tm];
            const float4 bv = *reinterpret_cast<const float4*>(&Ws[k][tn*4]);
            acc[0] = fmaf(a, bv.x, acc[0]);
            acc[1] = fmaf(a, bv.y, acc[1]);
            acc[2] = fmaf(a, bv.z, acc[2]);
            acc[3] = fmaf(a, bv.w, acc[3]);
        }
        __syncthreads();
    }
    {
        const int gm = m0 + tm;
        const float s = (!wt && gm < 512) ? conv_w[gm*4+3] : 1.f;
        const int n = n0 + tn*4;
        unsigned short h[4], l[4];
#pragma unroll
        for (int j=0;j<4;j++) split2(acc[j]*s, h[j], l[j]);
        const int ks = n >> 5, r = (n >> 3) & 3, pos = n & 7;
        size_t off;
        if (wt) off = (size_t)ks*4096 + (r*128 + gm)*8 + pos;
        else    off = (size_t)((gm>>7)*16 + ks)*4096 + (r*128 + (gm&127))*8 + pos;
        *reinterpret_cast<ushort4*>(&Oh[off]) = make_ushort4(h[0],h[1],h[2],h[3]);
        *reinterpret_cast<ushort4*>(&Ol[off]) = make_ushort4(l[0],l[1],l[2],l[3]);
    }
}

// ---------------------------------------------------------------------------
// K1 v6b: fragment-direct bf16x3 GEMM, TM=64, 4 blocks/CU.  (unchanged)
// ---------------------------------------------------------------------------
__global__ __launch_bounds__(256,4) void mgemm6b(
    const unsigned short* __restrict__ AhT, const unsigned short* __restrict__ AlT,
    const unsigned short* __restrict__ BhT, const unsigned short* __restrict__ BlT,
    const float* __restrict__ bias,
    float* __restrict__ O0, __half* __restrict__ O1)
{
    constexpr int TN=128, WN=64;
    constexpr int NT = 2;
    constexpr int NK = 16;

    const int tid = threadIdx.x;
    const int mb = blockIdx.x, nb = blockIdx.y;
    const int m0 = mb * 64, n0 = nb * TN;
    const int lane = tid & 63, wid = tid >> 6;
    const int half = lane >> 5, l32 = lane & 31;
    const int wm = (wid >> 1) * 32;
    const int wn = (wid & 1) * WN;

    f32x16 acc[NT];
#pragma unroll
    for (int j=0;j<NT;j++)
#pragma unroll
      for (int r=0;r<16;r++) acc[j][r] = 0.f;

    const int gm = m0 + wm + l32;                     // this lane's A row
    const size_t Atile0 = (size_t)((gm>>7)*16)*4096;  // band base
    const int Ain = (gm & 127)*8;
    const unsigned short* Bh0 = BhT + (size_t)nb*NK*4096;
    const unsigned short* Bl0 = BlT + (size_t)nb*NK*4096;

#pragma unroll
    for (int k=0; k<NK; ++k){
        const size_t at = Atile0 + (size_t)k*4096 + Ain;
        bf16x8 ah[2], al[2], bh[2][NT], bl[2][NT];
#pragma unroll
        for (int j=0;j<2;j++){
            const int r = j*2 + half;
            ah[j] = *reinterpret_cast<const bf16x8*>(&AhT[at + r*1024]);
            al[j] = *reinterpret_cast<const bf16x8*>(&AlT[at + r*1024]);
#pragma unroll
            for (int nt=0; nt<NT; ++nt){
                const size_t off = (size_t)k*4096 + (r*TN + wn + nt*32 + l32)*8;
                bh[j][nt] = *reinterpret_cast<const bf16x8*>(&Bh0[off]);
                bl[j][nt] = *reinterpret_cast<const bf16x8*>(&Bl0[off]);
            }
        }
#pragma unroll
        for (int j=0;j<2;j++){
#pragma unroll
            for (int nt=0; nt<NT; ++nt)
                acc[nt] = __builtin_amdgcn_mfma_f32_32x32x16_bf16(ah[j], bh[j][nt], acc[nt], 0,0,0);
#pragma unroll
            for (int nt=0; nt<NT; ++nt)
                acc[nt] = __builtin_amdgcn_mfma_f32_32x32x16_bf16(al[j], bh[j][nt], acc[nt], 0,0,0);
#pragma unroll
            for (int nt=0; nt<NT; ++nt)
                acc[nt] = __builtin_amdgcn_mfma_f32_32x32x16_bf16(ah[j], bl[j][nt], acc[nt], 0,0,0);
        }
    }

    // C/D: col=lane&31, row=(r&3)+8*(r>>2)+4*half  [m74/m101]
#pragma unroll
    for (int nt=0; nt<NT; ++nt)
#pragma unroll
    for (int r=0; r<16; ++r){
        const int row = m0 + wm + (r&3) + 8*(r>>2) + 4*half;
        const int col = n0 + wn + nt*32 + l32;
        float v = acc[nt][r] + bias[col];
        if (col < 512) O0[(size_t)row*512 + col] = v * fsig(v);
        else           O1[(size_t)row*512 + (col-512)] = __float2half(v);
    }
}

// ---------------------------------------------------------------------------
// Fused tail v4: 3-way independent accumulator chains (hh/lh/hl) in BOTH
//  MFMA phases. Per k-step the 3 bf16x3 passes are now mutually independent
//  -> 3x ILP on the matrix pipe (the dep-chain was the stall at 2 waves/SIMD).
//  Final combine: (hh + lh) + hl  (FP reorder; error ~ulp of partials).
// ---------------------------------------------------------------------------
__global__ __launch_bounds__(256,2) void tail_fused4(
    const float* __restrict__ Uf, const __half* __restrict__ Zh,
    const unsigned short* __restrict__ XphT, const unsigned short* __restrict__ XplT,
    const unsigned short* __restrict__ WthT, const unsigned short* __restrict__ WtlT,
    const float* __restrict__ dtw, const float* __restrict__ dtb,
    const float* __restrict__ dskip,
    const float* __restrict__ mu_b, const float* __restrict__ ls_b,
    float* __restrict__ mu_o, float* __restrict__ ls_o)
{
    constexpr int TM = 16;
    constexpr int ROWB = 136;              // shorts per kk-plane: 16 rows * 8 + 8 pad
    __shared__ unsigned short sYh[2][16*ROWB];
    __shared__ unsigned short sYl[2][16*ROWB];
    __shared__ float sxd[TM][49];
    __shared__ float sBC[TM];

    const int tid = threadIdx.x;
    const int m0 = blockIdx.x * TM;
    const int lane = tid & 63, wid = tid >> 6;
    const int quad = lane >> 4, l16 = lane & 15;
    const int q = wid;                      // wave -> 4 rows (q*4 .. q*4+3)

    // ---- upfront stream loads: consumed in phase 2, hidden under phase 1 ----
    float2 uvp[4][4]; __half2 zvp[4][4];
#pragma unroll
    for (int c=0;c<4;++c){
        const int d0 = c*128 + 2*lane;
#pragma unroll
        for (int rr=0; rr<4; ++rr){
            const size_t off = (size_t)(m0 + q*4 + rr)*512 + d0;
            uvp[c][rr] = *reinterpret_cast<const float2*>(&Uf[off]);
            zvp[c][rr] = *reinterpret_cast<const __half2*>(&Zh[off]);
        }
    }
    float2 dbp[4], dkp[4];
#pragma unroll
    for (int c=0;c<4;++c){
        const int d0 = c*128 + 2*lane;
        dbp[c] = *reinterpret_cast<const float2*>(&dtb[d0]);
        dkp[c] = *reinterpret_cast<const float2*>(&dskip[d0]);
    }

    // ---------------- phase 1: xdbl GEMM, 3 independent chains ----------------
    f32x4 ahh = (f32x4){0.f,0.f,0.f,0.f};
    f32x4 alh = (f32x4){0.f,0.f,0.f,0.f};
    f32x4 ahl = (f32x4){0.f,0.f,0.f,0.f};
    const float* arow = Uf + (size_t)(m0 + l16)*512 + quad*8;
    const int bxp = (quad*64 + wid*16 + l16)*8;   // Xp tile: [r=quad][n][8]
#pragma unroll
    for (int k=0; k<16; ++k){
        const float4 a0 = *reinterpret_cast<const float4*>(arow + k*32);
        const float4 a1 = *reinterpret_cast<const float4*>(arow + k*32 + 4);
        const bf16x8 bh = *reinterpret_cast<const bf16x8*>(&XphT[(size_t)k*2048 + bxp]);
        const bf16x8 bl = *reinterpret_cast<const bf16x8*>(&XplT[(size_t)k*2048 + bxp]);
        bf16x8 ah, al;
        {
            const float a[8] = {a0.x,a0.y,a0.z,a0.w,a1.x,a1.y,a1.z,a1.w};
            unsigned short h[8], l[8];
#pragma unroll
            for (int j=0;j<8;j++) split2(a[j], h[j], l[j]);
#pragma unroll
            for (int j=0;j<8;j++){ ah[j] = (short)h[j]; al[j] = (short)l[j]; }
        }
        ahh = __builtin_amdgcn_mfma_f32_16x16x32_bf16(ah, bh, ahh, 0,0,0);
        alh = __builtin_amdgcn_mfma_f32_16x16x32_bf16(al, bh, alh, 0,0,0);
        ahl = __builtin_amdgcn_mfma_f32_16x16x32_bf16(ah, bl, ahl, 0,0,0);
    }
    f32x4 acc;
#pragma unroll
    for (int r=0;r<4;++r) acc[r] = (ahh[r] + alh[r]) + ahl[r];

    // park xdbl (C layout: col=l16, row=quad*4+r), then BC dot
    {
        const int colp = wid*16 + l16;
        if (colp < 48){
#pragma unroll
            for (int r=0;r<4;++r) sxd[quad*4 + r][colp] = acc[r];
        }
    }
    __syncthreads();
    if (tid < TM){
        float bc = 0.f;
#pragma unroll
        for (int n=0;n<16;n++) bc = fmaf(sxd[tid][16+n], sxd[tid][32+n], bc);
        sBC[tid] = bc;
    }
    __syncthreads();                        // sBC/sxd visible to all waves

    // ---------------- phase 2: SSM chunks + out GEMM, 3 chains ----------------
    f32x4 ohh[2], olh[2], ohl[2];
#pragma unroll
    for (int j=0;j<2;j++){
        ohh[j] = (f32x4){0.f,0.f,0.f,0.f};
        olh[j] = (f32x4){0.f,0.f,0.f,0.f};
        ohl[j] = (f32x4){0.f,0.f,0.f,0.f};
    }

    const unsigned ybase = (unsigned)(lane >> 2)*68 + (unsigned)(lane & 3);  // dword idx

#pragma unroll
    for (int c=0; c<4; ++c){
        const int d0 = c*128 + 2*lane, d1 = d0 + 1;
        float w0[16], w1[16];
#pragma unroll
        for (int j=0;j<4;j++){
            const float4 a = *reinterpret_cast<const float4*>(&dtw[d0*16 + j*4]);
            w0[j*4]=a.x; w0[j*4+1]=a.y; w0[j*4+2]=a.z; w0[j*4+3]=a.w;
            const float4 b = *reinterpret_cast<const float4*>(&dtw[d1*16 + j*4]);
            w1[j*4]=b.x; w1[j*4+1]=b.y; w1[j*4+2]=b.z; w1[j*4+3]=b.w;
        }
        const float db0 = dbp[c].x, db1 = dbp[c].y;
        const float dk0 = dkp[c].x, dk1 = dkp[c].y;

        unsigned short* yh = sYh[c&1];
        unsigned short* yl = sYl[c&1];
#pragma unroll
        for (int rr=0; rr<4; ++rr){
            const int r = q*4 + rr;
            float xr[16];
#pragma unroll
            for (int j=0;j<16;j++) xr[j] = sxd[r][j];
            const float bc = sBC[r];
            float t0 = db0, t1 = db1;
#pragma unroll
            for (int j=0;j<16;j++){ t0 = fmaf(xr[j], w0[j], t0); t1 = fmaf(xr[j], w1[j], t1); }
            const float dl0 = (t0 > 20.f) ? t0 : __logf(1.f + __expf(t0));
            const float dl1 = (t1 > 20.f) ? t1 : __logf(1.f + __expf(t1));
            const float2 uv = uvp[c][rr];
            const __half2 zv = zvp[c][rr];
            const float z0 = __low2float(zv), z1 = __high2float(zv);
            const float y0 = uv.x * fmaf(dl0, bc, dk0) * (z0 * fsig(z0));
            const float y1 = uv.y * fmaf(dl1, bc, dk1) * (z1 * fsig(z1));
            unsigned short h0,l0,h1,l1;
            split2(y0,h0,l0); split2(y1,h1,l1);
            reinterpret_cast<unsigned*>(yh)[ybase + r*4] = (unsigned)h0 | ((unsigned)h1<<16);
            reinterpret_cast<unsigned*>(yl)[ybase + r*4] = (unsigned)l0 | ((unsigned)l1<<16);
        }
        __syncthreads();                    // sY[c&1] visible

#pragma unroll
        for (int s=0; s<4; ++s){
            const int kt = c*4 + s;         // global 32-k tile index
            const int aoff = (4*s + quad)*ROWB + l16*8;
            const bf16x8 ya = *reinterpret_cast<const bf16x8*>(&yh[aoff]);
            const bf16x8 yl8 = *reinterpret_cast<const bf16x8*>(&yl[aoff]);
            bf16x8 bh2[2], bl2[2];
#pragma unroll
            for (int nt=0; nt<2; ++nt){
                const size_t boff = (size_t)kt*4096 + (quad*128 + wid*32 + nt*16 + l16)*8;
                bh2[nt] = *reinterpret_cast<const bf16x8*>(&WthT[boff]);
                bl2[nt] = *reinterpret_cast<const bf16x8*>(&WtlT[boff]);
            }
#pragma unroll
            for (int nt=0; nt<2; ++nt)
                ohh[nt] = __builtin_amdgcn_mfma_f32_16x16x32_bf16(ya, bh2[nt], ohh[nt], 0,0,0);
#pragma unroll
            for (int nt=0; nt<2; ++nt)
                olh[nt] = __builtin_amdgcn_mfma_f32_16x16x32_bf16(yl8, bh2[nt], olh[nt], 0,0,0);
#pragma unroll
            for (int nt=0; nt<2; ++nt)
                ohl[nt] = __builtin_amdgcn_mfma_f32_16x16x32_bf16(ya, bl2[nt], ohl[nt], 0,0,0);
        }
    }

#pragma unroll
    for (int nt=0; nt<2; ++nt)
#pragma unroll
    for (int r=0; r<4; ++r){
        const int row = m0 + quad*4 + r;
        const int col = wid*32 + nt*16 + l16;
        const float v = (ohh[nt][r] + olh[nt][r]) + ohl[nt][r];
        if (col < 64) mu_o[(size_t)row*64 + col] = ftanh(v + mu_b[col]);
        else          ls_o[(size_t)row*64 + (col-64)] = fminf(fmaxf(v + ls_b[col-64], -5.f), 2.f);
    }
}

extern "C" void kernel_launch(void* const* d_in, const int* in_sizes, int n_in,
                              void* d_out, int out_size, void* d_ws, size_t ws_size,
                              hipStream_t stream) {
    (void)in_sizes; (void)n_in; (void)out_size; (void)ws_size;
    const float* percep  = (const float*)d_in[0];
    const float* W_in    = (const float*)d_in[1];
    const float* b_in    = (const float*)d_in[2];
    const float* mu_w    = (const float*)d_in[3];
    const float* mu_b    = (const float*)d_in[4];
    const float* ls_w    = (const float*)d_in[5];
    const float* ls_b    = (const float*)d_in[6];
    const float* in_proj = (const float*)d_in[7];
    const float* conv_w  = (const float*)d_in[8];
    const float* conv_b  = (const float*)d_in[9];
    const float* x_proj  = (const float*)d_in[10];
    const float* dt_w    = (const float*)d_in[11];
    const float* dt_b    = (const float*)d_in[12];
    // d_in[13] A_log unused at L=1 (h0=0)
    const float* Dskip   = (const float*)d_in[14];
    const float* out_proj= (const float*)d_in[15];

    char* ws = (char*)d_ws;
    const size_t MB = 1u<<20;
    unsigned short* W1h = (unsigned short*)(ws);                      // 1 MB (tiled)
    unsigned short* W1l = (unsigned short*)(ws + 1*MB);               // 1 MB
    unsigned short* Wth = (unsigned short*)(ws + 2*MB);               // 128 KB (tiled)
    unsigned short* Wtl = (unsigned short*)(ws + 2*MB + 128*1024);    // 128 KB
    unsigned short* Xph = (unsigned short*)(ws + 2*MB + 256*1024);    // 64 KB (tiled)
    unsigned short* Xpl = (unsigned short*)(ws + 2*MB + 320*1024);    // 64 KB
    float*          b1  = (float*)         (ws + 2*MB + 384*1024);    // 4 KB
    unsigned short* Ph  = (unsigned short*)(ws + 4*MB);               // 8 MB (tiled)
    unsigned short* Pl  = (unsigned short*)(ws + 12*MB);              // 8 MB
    float*          Uf  = (float*)         (ws + 20*MB);              // 16 MB
    __half*         Zh  = (__half*)        (ws + 36*MB);              // 8 MB

    float* mu_o = (float*)d_out;
    float* ls_o = (float*)d_out + (size_t)BATCH*64;

    dim3 blk(256);
    prep_all<<<dim3(102,16), blk, 0, stream>>>(
        percep, in_proj, W_in, b_in, mu_w, ls_w, conv_w, conv_b, out_proj, x_proj,
        W1h, W1l, Wth, Wtl, Xph, Xpl, Ph, Pl, b1);
    // K1 v6b: fragment-direct, TM=64 -> 4 blocks/CU
    mgemm6b<<<dim3(128,8), blk, 0, stream>>>(
        Ph, Pl, W1h, W1l, b1, Uf, Zh);
    // fused tail v4: 3-way independent MFMA chains
    tail_fused4<<<dim3(BATCH/16), blk, 0, stream>>>(
        Uf, Zh, Xph, Xpl, Wth, Wtl, dt_w, dt_b, Dskip, mu_b, ls_b, mu_o, ls_o);
}

// Round 8
// 164.121 us; speedup vs baseline: 1.0480x; 1.0480x over previous
//
#include <hip/hip_runtime.h>
#include <hip/hip_fp16.h>
#include <cmath>

#define BATCH 8192

typedef short bf16x8 __attribute__((ext_vector_type(8)));
typedef float f32x4 __attribute__((ext_vector_type(4)));
typedef float f32x16 __attribute__((ext_vector_type(16)));

__device__ __forceinline__ void split2(float x, unsigned short& h, unsigned short& l){
    unsigned u = __float_as_uint(x);
    unsigned hr = u + 0x7fffu + ((u >> 16) & 1u);
    unsigned short hs = (unsigned short)(hr >> 16);
    float hf = __uint_as_float(((unsigned)hs) << 16);
    float d = x - hf;
    unsigned v = __float_as_uint(d);
    unsigned short ls = (unsigned short)((v + 0x7fffu + ((v >> 16) & 1u)) >> 16);
    h = hs; l = ls;
}
__device__ __forceinline__ float fsig(float x){ return 1.f / (1.f + __expf(-x)); }
__device__ __forceinline__ float ftanh(float x){
    x = fminf(fmaxf(x, -10.f), 10.f);
    const float e = __expf(2.f*x);
    return (e - 1.f) / (e + 1.f);
}

// Tiled staged layouts (prepared by prep_all, consumed by fragment-direct loads).
// P:  tile (band in [0,64), ks in [0,16)): image [r(4)][m(128)][8] = 4096 shorts
// W1: tile (nb in [0,8),  ks in [0,16)):  image [r(4)][n(128)][8] = 4096 shorts
// Xp: tile (ks in [0,16)): image [r(4)][n(64)][8] = 2048 shorts
// Wt: tile (ks in [0,16)): image [r(4)][n(128)][8] = 4096 shorts
// The tiled image IS the MFMA fragment order -> fragments load straight from
// global (L2-resident), no LDS bounce, no barriers in the GEMM.

// ---------------------------------------------------------------------------
// Preprocessing, wide-parallel.  grid (102, 16)  (unchanged from R6)
// ---------------------------------------------------------------------------
__global__ __launch_bounds__(256) void prep_all(
    const float* __restrict__ percep,
    const float* __restrict__ in_proj, const float* __restrict__ W_in,
    const float* __restrict__ b_in,
    const float* __restrict__ mu_w, const float* __restrict__ ls_w,
    const float* __restrict__ conv_w, const float* __restrict__ conv_b,
    const float* __restrict__ out_proj, const float* __restrict__ x_proj,
    unsigned short* __restrict__ W1h, unsigned short* __restrict__ W1l,
    unsigned short* __restrict__ Wth, unsigned short* __restrict__ Wtl,
    unsigned short* __restrict__ Xph, unsigned short* __restrict__ Xpl,
    unsigned short* __restrict__ Ph, unsigned short* __restrict__ Pl,
    float* __restrict__ b1)
{
    __shared__ float As[16][33];
    __shared__ float Ws[16][36];
    __shared__ unsigned short Lh[4096];
    __shared__ unsigned short Ll[4096];

    const int bx = blockIdx.x, by = blockIdx.y;
    const int tid = threadIdx.x;

    if (bx >= 38){
        // one (band, ks) tile per block
        const int s = (bx-38)*16 + by;
        const int band = s >> 4, ks = s & 15;
        const size_t tbase = (size_t)s*4096;
#pragma unroll
        for (int g=0; g<2; ++g){
            const int u = g*256 + tid;
            const int row = u >> 2, piece = u & 3;
            const float* src = percep + (size_t)(band*128 + row)*512 + ks*32 + piece*8;
            const float4 v0 = *reinterpret_cast<const float4*>(src);
            const float4 v1 = *reinterpret_cast<const float4*>(src+4);
            unsigned short h[8], l[8];
            split2(v0.x,h[0],l[0]); split2(v0.y,h[1],l[1]);
            split2(v0.z,h[2],l[2]); split2(v0.w,h[3],l[3]);
            split2(v1.x,h[4],l[4]); split2(v1.y,h[5],l[5]);
            split2(v1.z,h[6],l[6]); split2(v1.w,h[7],l[7]);
            uint4 H, L;
            H.x=(unsigned)h[0]|((unsigned)h[1]<<16); H.y=(unsigned)h[2]|((unsigned)h[3]<<16);
            H.z=(unsigned)h[4]|((unsigned)h[5]<<16); H.w=(unsigned)h[6]|((unsigned)h[7]<<16);
            L.x=(unsigned)l[0]|((unsigned)l[1]<<16); L.y=(unsigned)l[2]|((unsigned)l[3]<<16);
            L.z=(unsigned)l[4]|((unsigned)l[5]<<16); L.w=(unsigned)l[6]|((unsigned)l[7]<<16);
            const int off = piece*1024 + row*8;
            *reinterpret_cast<uint4*>(&Lh[off]) = H;
            *reinterpret_cast<uint4*>(&Ll[off]) = L;
        }
        __syncthreads();
#pragma unroll
        for (int g=0; g<2; ++g){
            const int f = g*256 + tid;
            *reinterpret_cast<uint4*>(&Ph[tbase + f*8]) = *reinterpret_cast<const uint4*>(&Lh[f*8]);
            *reinterpret_cast<uint4*>(&Pl[tbase + f*8]) = *reinterpret_cast<const uint4*>(&Ll[f*8]);
        }
        return;
    }
    if (bx == 36){
        // b1[n] = in_proj[n,:].b_in ; 16 blocks x (4 waves x 16 rows)
        const int lane = tid & 63, w = tid >> 6;
        const float4 bv = *reinterpret_cast<const float4*>(&b_in[lane*4]);
        const int nbase = by*64 + w*16;
#pragma unroll 4
        for (int i=0;i<16;i++){
            const int n = nbase + i;
            const float4 av = *reinterpret_cast<const float4*>(&in_proj[(size_t)n*256 + lane*4]);
            float p = av.x*bv.x + av.y*bv.y + av.z*bv.z + av.w*bv.w;
#pragma unroll
            for (int off=32; off; off>>=1) p += __shfl_xor(p, off, 64);
            if (lane == 0)
                b1[n] = (n < 512) ? fmaf(p, conv_w[n*4+3], conv_b[n]) : p;
        }
        return;
    }
    if (bx == 37){
        // Xp: one ks tile (by = ks): cols c0..c0+31, rows 0..63
        const int c0 = by*32;
#pragma unroll
        for (int p=0;p<8;p++){
            const int idx = p*256 + tid;
            const int rrow = idx >> 5;
            const int c = c0 + (idx & 31);
            const float v = (rrow < 48) ? x_proj[(size_t)rrow*512 + c] : 0.f;
            unsigned short h,l; split2(v,h,l);
            const int ks = c >> 5, r = (c >> 3) & 3, pos = c & 7;
            const size_t off = (size_t)ks*2048 + (r*64 + rrow)*8 + pos;
            Xph[off]=h; Xpl[off]=l;
        }
        return;
    }
    // ---- weight GEMM, 32x32 output tile ----
    const float* A; unsigned short *Oh, *Ol; int m0; bool wt;
    const float* B;
    if (bx < 32){ A = in_proj + (size_t)bx*32*256; B = W_in; Oh=W1h; Ol=W1l; m0=bx*32; wt=false; }
    else {
        const int t = bx - 32;
        A = (t < 2) ? (mu_w + (size_t)t*32*256) : (ls_w + (size_t)(t-2)*32*256);
        B = out_proj; Oh=Wth; Ol=Wtl; m0=t*32; wt=true;
    }
    const int n0 = by*32;

    const int tm = tid >> 3, tn = tid & 7;   // 32 rows x 8 col-quads
    float acc[4] = {0.f,0.f,0.f,0.f};

    for (int k0=0;k0<256;k0+=16){
        {
            const int row = tid >> 3, kf = (tid & 7)*2;
            const float2 v = *reinterpret_cast<const float2*>(A + (size_t)row*256 + k0 + kf);
            As[kf][row] = v.x; As[kf+1][row] = v.y;
        }
        {
            const int kk = tid >> 4, c = (tid & 15)*2;
            const float2 v = *reinterpret_cast<const float2*>(B + (size_t)(k0+kk)*512 + n0 + c);
            Ws[kk][c] = v.x; Ws[kk][c+1] = v.y;
        }
        __syncthreads();
#pragma unroll
        for (int k=0;k<16;k++){
            const float a = As[k][tm];
            const float4 bv = *reinterpret_cast<const float4*>(&Ws[k][tn*4]);
            acc[0] = fmaf(a, bv.x, acc[0]);
            acc[1] = fmaf(a, bv.y, acc[1]);
            acc[2] = fmaf(a, bv.z, acc[2]);
            acc[3] = fmaf(a, bv.w, acc[3]);
        }
        __syncthreads();
    }
    {
        const int gm = m0 + tm;
        const float s = (!wt && gm < 512) ? conv_w[gm*4+3] : 1.f;
        const int n = n0 + tn*4;
        unsigned short h[4], l[4];
#pragma unroll
        for (int j=0;j<4;j++) split2(acc[j]*s, h[j], l[j]);
        const int ks = n >> 5, r = (n >> 3) & 3, pos = n & 7;
        size_t off;
        if (wt) off = (size_t)ks*4096 + (r*128 + gm)*8 + pos;
        else    off = (size_t)((gm>>7)*16 + ks)*4096 + (r*128 + (gm&127))*8 + pos;
        *reinterpret_cast<ushort4*>(&Oh[off]) = make_ushort4(h[0],h[1],h[2],h[3]);
        *reinterpret_cast<ushort4*>(&Ol[off]) = make_ushort4(l[0],l[1],l[2],l[3]);
    }
}

// ---------------------------------------------------------------------------
// K1 v6b: fragment-direct bf16x3 GEMM, TM=64, 4 blocks/CU.  (unchanged from R6)
// ---------------------------------------------------------------------------
__global__ __launch_bounds__(256,4) void mgemm6b(
    const unsigned short* __restrict__ AhT, const unsigned short* __restrict__ AlT,
    const unsigned short* __restrict__ BhT, const unsigned short* __restrict__ BlT,
    const float* __restrict__ bias,
    float* __restrict__ O0, __half* __restrict__ O1)
{
    constexpr int TN=128, WN=64;
    constexpr int NT = 2;
    constexpr int NK = 16;

    const int tid = threadIdx.x;
    const int mb = blockIdx.x, nb = blockIdx.y;
    const int m0 = mb * 64, n0 = nb * TN;
    const int lane = tid & 63, wid = tid >> 6;
    const int half = lane >> 5, l32 = lane & 31;
    const int wm = (wid >> 1) * 32;
    const int wn = (wid & 1) * WN;

    f32x16 acc[NT];
#pragma unroll
    for (int j=0;j<NT;j++)
#pragma unroll
      for (int r=0;r<16;r++) acc[j][r] = 0.f;

    const int gm = m0 + wm + l32;                     // this lane's A row
    const size_t Atile0 = (size_t)((gm>>7)*16)*4096;  // band base
    const int Ain = (gm & 127)*8;
    const unsigned short* Bh0 = BhT + (size_t)nb*NK*4096;
    const unsigned short* Bl0 = BlT + (size_t)nb*NK*4096;

#pragma unroll
    for (int k=0; k<NK; ++k){
        const size_t at = Atile0 + (size_t)k*4096 + Ain;
        bf16x8 ah[2], al[2], bh[2][NT], bl[2][NT];
#pragma unroll
        for (int j=0;j<2;j++){
            const int r = j*2 + half;
            ah[j] = *reinterpret_cast<const bf16x8*>(&AhT[at + r*1024]);
            al[j] = *reinterpret_cast<const bf16x8*>(&AlT[at + r*1024]);
#pragma unroll
            for (int nt=0; nt<NT; ++nt){
                const size_t off = (size_t)k*4096 + (r*TN + wn + nt*32 + l32)*8;
                bh[j][nt] = *reinterpret_cast<const bf16x8*>(&Bh0[off]);
                bl[j][nt] = *reinterpret_cast<const bf16x8*>(&Bl0[off]);
            }
        }
#pragma unroll
        for (int j=0;j<2;j++){
#pragma unroll
            for (int nt=0; nt<NT; ++nt)
                acc[nt] = __builtin_amdgcn_mfma_f32_32x32x16_bf16(ah[j], bh[j][nt], acc[nt], 0,0,0);
#pragma unroll
            for (int nt=0; nt<NT; ++nt)
                acc[nt] = __builtin_amdgcn_mfma_f32_32x32x16_bf16(al[j], bh[j][nt], acc[nt], 0,0,0);
#pragma unroll
            for (int nt=0; nt<NT; ++nt)
                acc[nt] = __builtin_amdgcn_mfma_f32_32x32x16_bf16(ah[j], bl[j][nt], acc[nt], 0,0,0);
        }
    }

    // C/D: col=lane&31, row=(r&3)+8*(r>>2)+4*half  [m74/m101]
#pragma unroll
    for (int nt=0; nt<NT; ++nt)
#pragma unroll
    for (int r=0; r<16; ++r){
        const int row = m0 + wm + (r&3) + 8*(r>>2) + 4*half;
        const int col = n0 + wn + nt*32 + l32;
        float v = acc[nt][r] + bias[col];
        if (col < 512) O0[(size_t)row*512 + col] = v * fsig(v);
        else           O1[(size_t)row*512 + (col-512)] = __float2half(v);
    }
}

// ---------------------------------------------------------------------------
// Fused tail v5 = v3 + coalesced LDS staging of the Uf tile.
//  v3's phase-1 A-load was a 64-cache-line scatter per instruction (lane
//  stride = one 2KB row) — the same pattern that provably cost mgemm7 +11us.
//  Now: 16x512 f32 Uf tile staged to LDS coalesced (1KB/wave-instr), padded
//  row stride 516 floats (<=4-way bank aliasing). Phase-1 fragments and the
//  SSM's u-values read from LDS. Values & FP order bit-identical to v3.
// ---------------------------------------------------------------------------
__global__ __launch_bounds__(256,2) void tail_fused5(
    const float* __restrict__ Uf, const __half* __restrict__ Zh,
    const unsigned short* __restrict__ XphT, const unsigned short* __restrict__ XplT,
    const unsigned short* __restrict__ WthT, const unsigned short* __restrict__ WtlT,
    const float* __restrict__ dtw, const float* __restrict__ dtb,
    const float* __restrict__ dskip,
    const float* __restrict__ mu_b, const float* __restrict__ ls_b,
    float* __restrict__ mu_o, float* __restrict__ ls_o)
{
    constexpr int TM = 16;
    constexpr int ROWB = 136;              // shorts per kk-plane: 16 rows * 8 + 8 pad
    constexpr int UPAD = 516;              // f32 row stride in sU (bank-spread)
    __shared__ unsigned short sYh[2][16*ROWB];
    __shared__ unsigned short sYl[2][16*ROWB];
    __shared__ float sxd[TM][49];
    __shared__ float sBC[TM];
    __shared__ float sU[16*UPAD];          // 33 KB: this block's 16x512 Uf tile

    const int tid = threadIdx.x;
    const int m0 = blockIdx.x * TM;
    const int lane = tid & 63, wid = tid >> 6;
    const int quad = lane >> 4, l16 = lane & 15;
    const int q = wid;                      // wave -> 4 rows (q*4 .. q*4+3)

    // ---- stage Uf tile into LDS, fully coalesced (256 thr x 8 float4) ----
#pragma unroll
    for (int it=0; it<8; ++it){
        const int idx = it*256 + tid;
        const int row = idx >> 7, piece = (idx & 127)*4;   // 128 float4 per row
        const float4 v = *reinterpret_cast<const float4*>(&Uf[(size_t)(m0+row)*512 + piece]);
        *reinterpret_cast<float4*>(&sU[row*UPAD + piece]) = v;
    }

    // ---- upfront stream loads (coalesced): Zh, dtb, dskip ----
    __half2 zvp[4][4];
#pragma unroll
    for (int c=0;c<4;++c){
        const int d0 = c*128 + 2*lane;
#pragma unroll
        for (int rr=0; rr<4; ++rr)
            zvp[c][rr] = *reinterpret_cast<const __half2*>(&Zh[(size_t)(m0 + q*4 + rr)*512 + d0]);
    }
    float2 dbp[4], dkp[4];
#pragma unroll
    for (int c=0;c<4;++c){
        const int d0 = c*128 + 2*lane;
        dbp[c] = *reinterpret_cast<const float2*>(&dtb[d0]);
        dkp[c] = *reinterpret_cast<const float2*>(&dskip[d0]);
    }
    __syncthreads();                        // sU ready

    // u-values for the SSM, from LDS (bit-identical to the old global reads)
    float2 uvp[4][4];
#pragma unroll
    for (int c=0;c<4;++c){
        const int d0 = c*128 + 2*lane;
#pragma unroll
        for (int rr=0; rr<4; ++rr){
            const int r = q*4 + rr;
            uvp[c][rr] = make_float2(sU[r*UPAD + d0], sU[r*UPAD + d0 + 1]);
        }
    }

    // ---------------- phase 1: xdbl GEMM, fragments from LDS ----------------
    f32x4 acc = (f32x4){0.f,0.f,0.f,0.f};
    const float* arow = &sU[l16*UPAD + quad*8];
    const int bxp = (quad*64 + wid*16 + l16)*8;   // Xp tile: [r=quad][n][8]
#pragma unroll
    for (int k=0; k<16; ++k){
        const float4 a0 = *reinterpret_cast<const float4*>(arow + k*32);
        const float4 a1 = *reinterpret_cast<const float4*>(arow + k*32 + 4);
        const bf16x8 bh = *reinterpret_cast<const bf16x8*>(&XphT[(size_t)k*2048 + bxp]);
        const bf16x8 bl = *reinterpret_cast<const bf16x8*>(&XplT[(size_t)k*2048 + bxp]);
        bf16x8 ah, al;
        {
            const float a[8] = {a0.x,a0.y,a0.z,a0.w,a1.x,a1.y,a1.z,a1.w};
            unsigned short h[8], l[8];
#pragma unroll
            for (int j=0;j<8;j++) split2(a[j], h[j], l[j]);
#pragma unroll
            for (int j=0;j<8;j++){ ah[j] = (short)h[j]; al[j] = (short)l[j]; }
        }
        acc = __builtin_amdgcn_mfma_f32_16x16x32_bf16(ah, bh, acc, 0,0,0);
        acc = __builtin_amdgcn_mfma_f32_16x16x32_bf16(al, bh, acc, 0,0,0);
        acc = __builtin_amdgcn_mfma_f32_16x16x32_bf16(ah, bl, acc, 0,0,0);
    }

    // park xdbl (C layout: col=l16, row=quad*4+r), then BC dot
    {
        const int colp = wid*16 + l16;
        if (colp < 48){
#pragma unroll
            for (int r=0;r<4;++r) sxd[quad*4 + r][colp] = acc[r];
        }
    }
    __syncthreads();
    if (tid < TM){
        float bc = 0.f;
#pragma unroll
        for (int n=0;n<16;n++) bc = fmaf(sxd[tid][16+n], sxd[tid][32+n], bc);
        sBC[tid] = bc;
    }
    __syncthreads();                        // sBC/sxd visible to all waves

    // ---------------- phase 2: SSM chunks + out GEMM ----------------
    f32x4 oacc[2];
    oacc[0] = (f32x4){0.f,0.f,0.f,0.f};
    oacc[1] = (f32x4){0.f,0.f,0.f,0.f};

    const unsigned ybase = (unsigned)(lane >> 2)*68 + (unsigned)(lane & 3);  // dword idx

#pragma unroll
    for (int c=0; c<4; ++c){
        const int d0 = c*128 + 2*lane, d1 = d0 + 1;
        float w0[16], w1[16];
#pragma unroll
        for (int j=0;j<4;j++){
            const float4 a = *reinterpret_cast<const float4*>(&dtw[d0*16 + j*4]);
            w0[j*4]=a.x; w0[j*4+1]=a.y; w0[j*4+2]=a.z; w0[j*4+3]=a.w;
            const float4 b = *reinterpret_cast<const float4*>(&dtw[d1*16 + j*4]);
            w1[j*4]=b.x; w1[j*4+1]=b.y; w1[j*4+2]=b.z; w1[j*4+3]=b.w;
        }
        const float db0 = dbp[c].x, db1 = dbp[c].y;
        const float dk0 = dkp[c].x, dk1 = dkp[c].y;

        unsigned short* yh = sYh[c&1];
        unsigned short* yl = sYl[c&1];
#pragma unroll
        for (int rr=0; rr<4; ++rr){
            const int r = q*4 + rr;
            float xr[16];
#pragma unroll
            for (int j=0;j<16;j++) xr[j] = sxd[r][j];
            const float bc = sBC[r];
            float t0 = db0, t1 = db1;
#pragma unroll
            for (int j=0;j<16;j++){ t0 = fmaf(xr[j], w0[j], t0); t1 = fmaf(xr[j], w1[j], t1); }
            const float dl0 = (t0 > 20.f) ? t0 : __logf(1.f + __expf(t0));
            const float dl1 = (t1 > 20.f) ? t1 : __logf(1.f + __expf(t1));
            const float2 uv = uvp[c][rr];
            const __half2 zv = zvp[c][rr];
            const float z0 = __low2float(zv), z1 = __high2float(zv);
            const float y0 = uv.x * fmaf(dl0, bc, dk0) * (z0 * fsig(z0));
            const float y1 = uv.y * fmaf(dl1, bc, dk1) * (z1 * fsig(z1));
            unsigned short h0,l0,h1,l1;
            split2(y0,h0,l0); split2(y1,h1,l1);
            reinterpret_cast<unsigned*>(yh)[ybase + r*4] = (unsigned)h0 | ((unsigned)h1<<16);
            reinterpret_cast<unsigned*>(yl)[ybase + r*4] = (unsigned)l0 | ((unsigned)l1<<16);
        }
        __syncthreads();                    // sY[c&1] visible

#pragma unroll
        for (int s=0; s<4; ++s){
            const int kt = c*4 + s;         // global 32-k tile index
            const int aoff = (4*s + quad)*ROWB + l16*8;
            const bf16x8 ya = *reinterpret_cast<const bf16x8*>(&yh[aoff]);
            const bf16x8 yl8 = *reinterpret_cast<const bf16x8*>(&yl[aoff]);
            bf16x8 bh2[2], bl2[2];
#pragma unroll
            for (int nt=0; nt<2; ++nt){
                const size_t boff = (size_t)kt*4096 + (quad*128 + wid*32 + nt*16 + l16)*8;
                bh2[nt] = *reinterpret_cast<const bf16x8*>(&WthT[boff]);
                bl2[nt] = *reinterpret_cast<const bf16x8*>(&WtlT[boff]);
            }
#pragma unroll
            for (int nt=0; nt<2; ++nt)
                oacc[nt] = __builtin_amdgcn_mfma_f32_16x16x32_bf16(ya, bh2[nt], oacc[nt], 0,0,0);
#pragma unroll
            for (int nt=0; nt<2; ++nt)
                oacc[nt] = __builtin_amdgcn_mfma_f32_16x16x32_bf16(yl8, bh2[nt], oacc[nt], 0,0,0);
#pragma unroll
            for (int nt=0; nt<2; ++nt)
                oacc[nt] = __builtin_amdgcn_mfma_f32_16x16x32_bf16(ya, bl2[nt], oacc[nt], 0,0,0);
        }
    }

#pragma unroll
    for (int nt=0; nt<2; ++nt)
#pragma unroll
    for (int r=0; r<4; ++r){
        const int row = m0 + quad*4 + r;
        const int col = wid*32 + nt*16 + l16;
        const float v = oacc[nt][r];
        if (col < 64) mu_o[(size_t)row*64 + col] = ftanh(v + mu_b[col]);
        else          ls_o[(size_t)row*64 + (col-64)] = fminf(fmaxf(v + ls_b[col-64], -5.f), 2.f);
    }
}

extern "C" void kernel_launch(void* const* d_in, const int* in_sizes, int n_in,
                              void* d_out, int out_size, void* d_ws, size_t ws_size,
                              hipStream_t stream) {
    (void)in_sizes; (void)n_in; (void)out_size; (void)ws_size;
    const float* percep  = (const float*)d_in[0];
    const float* W_in    = (const float*)d_in[1];
    const float* b_in    = (const float*)d_in[2];
    const float* mu_w    = (const float*)d_in[3];
    const float* mu_b    = (const float*)d_in[4];
    const float* ls_w    = (const float*)d_in[5];
    const float* ls_b    = (const float*)d_in[6];
    const float* in_proj = (const float*)d_in[7];
    const float* conv_w  = (const float*)d_in[8];
    const float* conv_b  = (const float*)d_in[9];
    const float* x_proj  = (const float*)d_in[10];
    const float* dt_w    = (const float*)d_in[11];
    const float* dt_b    = (const float*)d_in[12];
    // d_in[13] A_log unused at L=1 (h0=0)
    const float* Dskip   = (const float*)d_in[14];
    const float* out_proj= (const float*)d_in[15];

    char* ws = (char*)d_ws;
    const size_t MB = 1u<<20;
    unsigned short* W1h = (unsigned short*)(ws);                      // 1 MB (tiled)
    unsigned short* W1l = (unsigned short*)(ws + 1*MB);               // 1 MB
    unsigned short* Wth = (unsigned short*)(ws + 2*MB);               // 128 KB (tiled)
    unsigned short* Wtl = (unsigned short*)(ws + 2*MB + 128*1024);    // 128 KB
    unsigned short* Xph = (unsigned short*)(ws + 2*MB + 256*1024);    // 64 KB (tiled)
    unsigned short* Xpl = (unsigned short*)(ws + 2*MB + 320*1024);    // 64 KB
    float*          b1  = (float*)         (ws + 2*MB + 384*1024);    // 4 KB
    unsigned short* Ph  = (unsigned short*)(ws + 4*MB);               // 8 MB (tiled)
    unsigned short* Pl  = (unsigned short*)(ws + 12*MB);              // 8 MB
    float*          Uf  = (float*)         (ws + 20*MB);              // 16 MB
    __half*         Zh  = (__half*)        (ws + 36*MB);              // 8 MB

    float* mu_o = (float*)d_out;
    float* ls_o = (float*)d_out + (size_t)BATCH*64;

    dim3 blk(256);
    prep_all<<<dim3(102,16), blk, 0, stream>>>(
        percep, in_proj, W_in, b_in, mu_w, ls_w, conv_w, conv_b, out_proj, x_proj,
        W1h, W1l, Wth, Wtl, Xph, Xpl, Ph, Pl, b1);
    // K1 v6b: fragment-direct, TM=64 -> 4 blocks/CU
    mgemm6b<<<dim3(128,8), blk, 0, stream>>>(
        Ph, Pl, W1h, W1l, b1, Uf, Zh);
    // fused tail v5: coalesced Uf staging in LDS
    tail_fused5<<<dim3(BATCH/16), blk, 0, stream>>>(
        Uf, Zh, Xph, Xpl, Wth, Wtl, dt_w, dt_b, Dskip, mu_b, ls_b, mu_o, ls_o);
}